// Round 6
// baseline (282.859 us; speedup 1.0000x reference)
//
#include <hip/hip_runtime.h>
#include <math.h>
#include <limits.h>

// RelativeBucketedTimeAndPositionBasedBias — B=16, N=2048, NUM_BUCKETS=128
// out[b,i,j] = pos_w[N-1 + j - i] + ts_w[bucket(b,i,j)]
//   diff = ext[b,i+1] - ext[b,j]; m = max(|diff·causal|, 1)  (integer, < 2^24)
//
// VERIFIED BIT-EXACT (R12-R14, absmax=0): ref pipeline is
//   bucket = clip(trunc( RN_f32( log32(m) * RN_f32(1/0.301f) ) ), 0, 128)
// realized as bucket(m) = max{ k : T[k] <= m } via exact integer thresholds T.
// DO NOT alter the predicate q(m) = (int)((float)log((double)m) * recip).
//
// Session ledger:
//  R15 272.1 | R16/17 nt+unroll16+prefetch bundle 283.1 (reverted)
//  R18 ws-free in-block build 273.2 (fills proved UNCONDITIONAL)
//  R19 single-hop etabT/etabW + causal-drop 271.3
//  R20 merged 1-launch setup + isolated t_next prefetch 270.6 (noise)
// Decomposition: ws 1-GiB poison ~163 (harness, at 6.6 TB/s ceiling)
//  + out poison ~42 + main ~55-60 (vs 43 us write floor) + setup/gaps ~5-10.
// R21: the ONE untested lever for main — nontemporal stores IN ISOLATION.
// R16's regression was the bundle (unroll16 likely, via reg pressure); R20
// cleared the prefetch; nt alone never measured. Mechanism: 268 MB write-once
// stream = 8.4x aggregate L2 of allocate+dirty+evict churn, competing with
// pos_w/ts residency. Values identical -> absmax 0. If neutral: ROOFLINE.

#define NN 2048
#define BLOCK 256
#define ROWS 16

typedef float f32x4 __attribute__((ext_vector_type(4)));

__device__ __forceinline__ int qbucket(long long m, float recip) {
    const float lg = (float)log((double)m);   // CR f32 log of integer m (f64 path)
    return (int)(lg * recip);                 // f32 RN multiply, trunc
}

// Merged setup: etabT[c] = (T[base+1], T[base+2], T[base+3], 0),
//               etabW[c] = (ts_w[base..base+3]),  base = q(2^E), E = 31-c.
// T[k] = min{m : q(m) >= k} searched within the octave (q monotone);
// INT_MAX if the boundary lies beyond the octave (compare never fires since
// mi < 2^(E+1) <= T). Octave spans ln(2)/0.301 = 2.303 buckets -> <=3
// boundaries: 3 slots suffice (R12-R14 invariant; R18/R20 verified builds).
__global__ void build_etab_kernel(const float* __restrict__ ts_w,
                                  int4* __restrict__ etabT,
                                  float4* __restrict__ etabW) {
    const int tid = threadIdx.x;           // 0..127
    if (tid >= 128) return;
    const int c = tid >> 2;                // octave's clz value 0..31
    const int s = tid & 3;                 // slot
    const float recip = (float)(1.0 / (double)0.301f);   // RN_f32(1/f32(0.301))
    const long long mE = 1LL << (31 - c);
    const int base = qbucket(mE, recip);

    // weight slot: etabW[c][s] = ts_w[min(base+s, 128)]
    ((float*)etabW)[c * 4 + s] = ts_w[min(base + s, 128)];

    // threshold slots: s=1..3 -> etabT[c][s-1] = T[base+s]; s=0 -> pad 0
    int* tflat = (int*)etabT;
    if (s == 0) {
        tflat[c * 4 + 3] = 0;
    } else {
        const long long hi0 = mE + mE - 1;
        const int k = base + s;            // target bucket boundary
        int t = INT_MAX;
        if (k <= 129 && qbucket(hi0, recip) >= k) {
            long long lo = mE, hi = hi0;
            while (lo < hi) {              // min m in octave with q(m) >= k
                const long long mid = (lo + hi) >> 1;
                if (qbucket(mid, recip) >= k) hi = mid; else lo = mid + 1;
            }
            t = (lo > (long long)INT_MAX) ? INT_MAX : (int)lo;
        }
        tflat[c * 4 + (s - 1)] = t;
    }
}

__device__ __forceinline__ float bias_elem(int t_next, int tj,
                                           const int4* __restrict__ sT,
                                           const float4* __restrict__ sW,
                                           float pv) {
    int mi = t_next - tj;                  // j<=i: >=0 (sorted); j>i: <=0
    mi = mi < 1 ? 1 : mi;                  // max(|td·causal|,1); j>i lands at 1
    const int c = __clz(mi);
    const int4 t = sT[c];                  // independent broadcast b128
    const float4 w = sW[c];                // independent broadcast b128
    // T non-decreasing within octave: weight of highest satisfied slot
    // == ts_w[base + (mi>=t.x)+(mi>=t.y)+(mi>=t.z)] (verified realization).
    float r = w.x;
    r = (mi >= t.x) ? w.y : r;
    r = (mi >= t.y) ? w.z : r;
    r = (mi >= t.z) ? w.w : r;
    return pv + r;
}

__global__ __launch_bounds__(BLOCK) void hstu_bias_kernel(
    const int* __restrict__ ts,       // [B, N] int32, sorted per row
    const float* __restrict__ pos_w,  // [2N-1]
    const int4* __restrict__ etabT,   // [32]
    const float4* __restrict__ etabW, // [32]
    float* __restrict__ out)          // [B, N, N]
{
    __shared__ int4 s_etabT[32];
    __shared__ float4 s_etabW[32];
    const int tid = threadIdx.x;
    if (tid < 32) {
        s_etabT[tid] = etabT[tid];
        s_etabW[tid] = etabW[tid];
    }

    const int grp = blockIdx.x;          // 0..2047
    const int b = grp >> 7;              // /128
    const int i0 = (grp & 127) << 4;     // *ROWS
    const int* __restrict__ ts_row = ts + b * NN;

    // ts columns are the same for all ROWS rows of this block: register-cache.
    const int j_0 = tid * 4;
    const int j_1 = tid * 4 + 1024;
    const int4 tj0 = *(const int4*)(ts_row + j_0);   // aligned 16B
    const int4 tj1 = *(const int4*)(ts_row + j_1);

    // R20(b): all 16 t_next values are wave-uniform & known now — prefetch
    // (scalar loads pipeline back-to-back instead of serializing per row).
    int tn[ROWS];
#pragma unroll
    for (int r = 0; r < ROWS; ++r) {
        const int i = i0 + r;
        tn[r] = ts_row[(i < NN - 1) ? (i + 1) : (NN - 1)];
    }

    __syncthreads();
    float* __restrict__ out_base = out + (size_t)(b * NN + i0) * NN;

#pragma unroll 4
    for (int r = 0; r < ROWS; ++r) {
        const int i = i0 + r;
        const int t_next = tn[r];
        const float* __restrict__ pw = pos_w + (NN - 1 - i);           // pw[j]
        f32x4* __restrict__ out4 = (f32x4*)(out_base + (size_t)r * NN);

        float4 pva, pvb;                         // 4B-aligned 16B loads (L1-hit)
        __builtin_memcpy(&pva, pw + j_0, 16);
        __builtin_memcpy(&pvb, pw + j_1, 16);

        f32x4 ra, rb;
        ra.x = bias_elem(t_next, tj0.x, s_etabT, s_etabW, pva.x);
        ra.y = bias_elem(t_next, tj0.y, s_etabT, s_etabW, pva.y);
        ra.z = bias_elem(t_next, tj0.z, s_etabT, s_etabW, pva.z);
        ra.w = bias_elem(t_next, tj0.w, s_etabT, s_etabW, pva.w);
        rb.x = bias_elem(t_next, tj1.x, s_etabT, s_etabW, pvb.x);
        rb.y = bias_elem(t_next, tj1.y, s_etabT, s_etabW, pvb.y);
        rb.z = bias_elem(t_next, tj1.z, s_etabT, s_etabW, pvb.z);
        rb.w = bias_elem(t_next, tj1.w, s_etabT, s_etabW, pvb.w);

        // R21: nt stores in isolation (no-allocate / early-evict in L2).
        __builtin_nontemporal_store(ra, out4 + tid);
        __builtin_nontemporal_store(rb, out4 + tid + 256);
    }
}

extern "C" void kernel_launch(void* const* d_in, const int* in_sizes, int n_in,
                              void* d_out, int out_size, void* d_ws, size_t ws_size,
                              hipStream_t stream) {
    const int* ts = (const int*)d_in[0];        // all_timestamps [16,2048]
    const float* ts_w = (const float*)d_in[1];  // [129]
    const float* pos_w = (const float*)d_in[2]; // [4095]
    float* out = (float*)d_out;                 // [16,2048,2048] f32
    int4* etabT = (int4*)d_ws;                  // [32] at ws+0   (16B aligned)
    float4* etabW = (float4*)((char*)d_ws + 512); // [32] at ws+512

    build_etab_kernel<<<dim3(1), dim3(128), 0, stream>>>(ts_w, etabT, etabW);

    const int B = 16;
    hstu_bias_kernel<<<dim3(B * NN / ROWS), dim3(BLOCK), 0, stream>>>(ts, pos_w, etabT, etabW, out);
}

// Round 7
// 268.606 us; speedup vs baseline: 1.0531x; 1.0531x over previous
//
#include <hip/hip_runtime.h>
#include <math.h>
#include <limits.h>

// RelativeBucketedTimeAndPositionBasedBias — B=16, N=2048, NUM_BUCKETS=128
// out[b,i,j] = pos_w[N-1 + j - i] + ts_w[bucket(b,i,j)]
//   diff = ext[b,i+1] - ext[b,j]; m = max(|diff·causal|, 1)  (integer, < 2^24)
//
// VERIFIED BIT-EXACT (R12-R14, absmax=0): ref pipeline is
//   bucket = clip(trunc( RN_f32( log32(m) * RN_f32(1/0.301f) ) ), 0, 128)
// realized as bucket(m) = max{ k : T[k] <= m } via exact integer thresholds T.
// DO NOT alter the predicate q(m) = (int)((float)log((double)m) * recip).
//
// Session ledger:
//  R15 272.1 | R16/17 nt+unroll16+prefetch bundle 283.1 (reverted)
//  R18 ws-free in-block build 273.2 (fills proved UNCONDITIONAL)
//  R19 single-hop etabT/etabW + causal-drop 271.3
//  R20 merged 1-launch setup + isolated t_next prefetch 270.6  <-- BEST
//  R21 isolated nt stores 282.9 — but fills drifted +4% same run (161-165 ->
//      168-178 us for identical 1-GiB fills): nt is neutral-to-negative.
//      REVERTED here.
// Final decomposition: ws 1-GiB poison ~163 + out poison ~42 (both harness-
// imposed, at the 6.5-6.6 TB/s measured write ceiling) + main ~55 (store-
// bound: insensitive to large compute +/-; prefetch & nt levers isolated-
// tested) + 1 setup launch/gaps ~5-10. Remaining controllable slack ~12 us
// (main vs 43 us floor) has no remaining untested lever.
// R22 = exact R20 kernel (re-anchor baseline). If ~270 reproduces: ROOFLINE.

#define NN 2048
#define BLOCK 256
#define ROWS 16

__device__ __forceinline__ int qbucket(long long m, float recip) {
    const float lg = (float)log((double)m);   // CR f32 log of integer m (f64 path)
    return (int)(lg * recip);                 // f32 RN multiply, trunc
}

// Merged setup: etabT[c] = (T[base+1], T[base+2], T[base+3], 0),
//               etabW[c] = (ts_w[base..base+3]),  base = q(2^E), E = 31-c.
// T[k] = min{m : q(m) >= k} searched within the octave (q monotone);
// INT_MAX if the boundary lies beyond the octave (compare never fires since
// mi < 2^(E+1) <= T). Octave spans ln(2)/0.301 = 2.303 buckets -> <=3
// boundaries: 3 slots suffice (R12-R14 invariant; R18/R20 verified builds).
__global__ void build_etab_kernel(const float* __restrict__ ts_w,
                                  int4* __restrict__ etabT,
                                  float4* __restrict__ etabW) {
    const int tid = threadIdx.x;           // 0..127
    if (tid >= 128) return;
    const int c = tid >> 2;                // octave's clz value 0..31
    const int s = tid & 3;                 // slot
    const float recip = (float)(1.0 / (double)0.301f);   // RN_f32(1/f32(0.301))
    const long long mE = 1LL << (31 - c);
    const int base = qbucket(mE, recip);

    // weight slot: etabW[c][s] = ts_w[min(base+s, 128)]
    ((float*)etabW)[c * 4 + s] = ts_w[min(base + s, 128)];

    // threshold slots: s=1..3 -> etabT[c][s-1] = T[base+s]; s=0 -> pad 0
    int* tflat = (int*)etabT;
    if (s == 0) {
        tflat[c * 4 + 3] = 0;
    } else {
        const long long hi0 = mE + mE - 1;
        const int k = base + s;            // target bucket boundary
        int t = INT_MAX;
        if (k <= 129 && qbucket(hi0, recip) >= k) {
            long long lo = mE, hi = hi0;
            while (lo < hi) {              // min m in octave with q(m) >= k
                const long long mid = (lo + hi) >> 1;
                if (qbucket(mid, recip) >= k) hi = mid; else lo = mid + 1;
            }
            t = (lo > (long long)INT_MAX) ? INT_MAX : (int)lo;
        }
        tflat[c * 4 + (s - 1)] = t;
    }
}

__device__ __forceinline__ float bias_elem(int t_next, int tj,
                                           const int4* __restrict__ sT,
                                           const float4* __restrict__ sW,
                                           float pv) {
    int mi = t_next - tj;                  // j<=i: >=0 (sorted); j>i: <=0
    mi = mi < 1 ? 1 : mi;                  // max(|td·causal|,1); j>i lands at 1
    const int c = __clz(mi);
    const int4 t = sT[c];                  // independent broadcast b128
    const float4 w = sW[c];                // independent broadcast b128
    // T non-decreasing within octave: weight of highest satisfied slot
    // == ts_w[base + (mi>=t.x)+(mi>=t.y)+(mi>=t.z)] (verified realization).
    float r = w.x;
    r = (mi >= t.x) ? w.y : r;
    r = (mi >= t.y) ? w.z : r;
    r = (mi >= t.z) ? w.w : r;
    return pv + r;
}

__global__ __launch_bounds__(BLOCK) void hstu_bias_kernel(
    const int* __restrict__ ts,       // [B, N] int32, sorted per row
    const float* __restrict__ pos_w,  // [2N-1]
    const int4* __restrict__ etabT,   // [32]
    const float4* __restrict__ etabW, // [32]
    float* __restrict__ out)          // [B, N, N]
{
    __shared__ int4 s_etabT[32];
    __shared__ float4 s_etabW[32];
    const int tid = threadIdx.x;
    if (tid < 32) {
        s_etabT[tid] = etabT[tid];
        s_etabW[tid] = etabW[tid];
    }

    const int grp = blockIdx.x;          // 0..2047
    const int b = grp >> 7;              // /128
    const int i0 = (grp & 127) << 4;     // *ROWS
    const int* __restrict__ ts_row = ts + b * NN;

    // ts columns are the same for all ROWS rows of this block: register-cache.
    const int j_0 = tid * 4;
    const int j_1 = tid * 4 + 1024;
    const int4 tj0 = *(const int4*)(ts_row + j_0);   // aligned 16B
    const int4 tj1 = *(const int4*)(ts_row + j_1);

    // All 16 t_next values are wave-uniform & known now — prefetch
    // (scalar loads pipeline back-to-back instead of serializing per row).
    int tn[ROWS];
#pragma unroll
    for (int r = 0; r < ROWS; ++r) {
        const int i = i0 + r;
        tn[r] = ts_row[(i < NN - 1) ? (i + 1) : (NN - 1)];
    }

    __syncthreads();
    float* __restrict__ out_base = out + (size_t)(b * NN + i0) * NN;

#pragma unroll 4
    for (int r = 0; r < ROWS; ++r) {
        const int i = i0 + r;
        const int t_next = tn[r];
        const float* __restrict__ pw = pos_w + (NN - 1 - i);           // pw[j]
        float4* __restrict__ out4 = (float4*)(out_base + (size_t)r * NN);

        float4 pva, pvb;                         // 4B-aligned 16B loads (L1-hit)
        __builtin_memcpy(&pva, pw + j_0, 16);
        __builtin_memcpy(&pvb, pw + j_1, 16);

        float4 ra, rb;
        ra.x = bias_elem(t_next, tj0.x, s_etabT, s_etabW, pva.x);
        ra.y = bias_elem(t_next, tj0.y, s_etabT, s_etabW, pva.y);
        ra.z = bias_elem(t_next, tj0.z, s_etabT, s_etabW, pva.z);
        ra.w = bias_elem(t_next, tj0.w, s_etabT, s_etabW, pva.w);
        rb.x = bias_elem(t_next, tj1.x, s_etabT, s_etabW, pvb.x);
        rb.y = bias_elem(t_next, tj1.y, s_etabT, s_etabW, pvb.y);
        rb.z = bias_elem(t_next, tj1.z, s_etabT, s_etabW, pvb.z);
        rb.w = bias_elem(t_next, tj1.w, s_etabT, s_etabW, pvb.w);

        out4[tid] = ra;
        out4[tid + 256] = rb;
    }
}

extern "C" void kernel_launch(void* const* d_in, const int* in_sizes, int n_in,
                              void* d_out, int out_size, void* d_ws, size_t ws_size,
                              hipStream_t stream) {
    const int* ts = (const int*)d_in[0];        // all_timestamps [16,2048]
    const float* ts_w = (const float*)d_in[1];  // [129]
    const float* pos_w = (const float*)d_in[2]; // [4095]
    float* out = (float*)d_out;                 // [16,2048,2048] f32
    int4* etabT = (int4*)d_ws;                  // [32] at ws+0   (16B aligned)
    float4* etabW = (float4*)((char*)d_ws + 512); // [32] at ws+512

    build_etab_kernel<<<dim3(1), dim3(128), 0, stream>>>(ts_w, etabT, etabW);

    const int B = 16;
    hstu_bias_kernel<<<dim3(B * NN / ROWS), dim3(BLOCK), 0, stream>>>(ts, pos_w, etabT, etabW, out);
}